// Round 9
// baseline (302.561 us; speedup 1.0000x reference)
//
#include <hip/hip_runtime.h>
#include <math.h>

#define N_NODES 50000
#define N_EDGES 500000
#define IN_CH 256
#define D1 512          // HEADS*HID
#define HEADS 8
#define HID 64
#define OUT_CH 16
#define NEG_SLOPE 0.2f

typedef __bf16 bf16x8 __attribute__((ext_vector_type(8)));
typedef float f32x4 __attribute__((ext_vector_type(4)));
typedef float f32x2 __attribute__((ext_vector_type(2)));

// convert 8 packed fp8 e4m3 (uint2) -> 8 floats via HW v_cvt_pk_f32_fp8
__device__ inline void fp8x8_to_f32(uint2 u, float* f) {
    f32x2 p0 = __builtin_amdgcn_cvt_pk_f32_fp8(u.x, false);
    f32x2 p1 = __builtin_amdgcn_cvt_pk_f32_fp8(u.x, true);
    f32x2 p2 = __builtin_amdgcn_cvt_pk_f32_fp8(u.y, false);
    f32x2 p3 = __builtin_amdgcn_cvt_pk_f32_fp8(u.y, true);
    f[0] = p0.x; f[1] = p0.y; f[2] = p1.x; f[3] = p1.y;
    f[4] = p2.x; f[5] = p2.y; f[6] = p3.x; f[7] = p3.y;
}

__device__ inline void fp8x16_to_f32(uint4 u, float* f) {
    fp8x8_to_f32(make_uint2(u.x, u.y), f);
    fp8x8_to_f32(make_uint2(u.z, u.w), f + 8);
}

__device__ inline unsigned char f32_to_fp8(float v) {
    return (unsigned char)(__builtin_amdgcn_cvt_pk_fp8_f32(v, v, 0, false) & 0xff);
}

__device__ inline float leaky_exp(float e) {
    float v = e > 0.f ? e : NEG_SLOPE * e;
    return __expf(v);
}

// async global->LDS, 16B per lane; LDS dest = wave-uniform base + lane*16
__device__ inline void gl_lds16(const __bf16* g, __bf16* l) {
    __builtin_amdgcn_global_load_lds(
        (const __attribute__((address_space(1))) unsigned int*)g,
        (__attribute__((address_space(3))) unsigned int*)l,
        16, 0, 0);
}

// pack 8 floats -> bf16x8
__device__ inline bf16x8 f32x8_to_bf16x8(const float4& a, const float4& b) {
    bf16x8 r;
    r[0] = (__bf16)a.x; r[1] = (__bf16)a.y; r[2] = (__bf16)a.z; r[3] = (__bf16)a.w;
    r[4] = (__bf16)b.x; r[5] = (__bf16)b.y; r[6] = (__bf16)b.z; r[7] = (__bf16)b.w;
    return r;
}

// ---------------- prep: W converts + edge histogram (deg pre-zeroed) --------
__global__ __launch_bounds__(256) void k_prep(const float* __restrict__ W1,
                                              const float* __restrict__ W2,
                                              const int* __restrict__ edst,
                                              __bf16* __restrict__ Wt,
                                              __bf16* __restrict__ Wt2,
                                              int* __restrict__ deg) {
    int t = blockIdx.x * 256 + threadIdx.x;
    int nthr = gridDim.x * 256;
    for (int i = t; i < D1 * IN_CH; i += nthr) {
        int n = i >> 8, k = i & 255;
        Wt[i] = (__bf16)W1[k * D1 + n];
    }
    for (int i = t; i < D1 * OUT_CH; i += nthr) {
        int n = i >> 9, k = i & 511;
        Wt2[i] = (__bf16)W2[k * OUT_CH + n];
    }
    for (int i = t; i < N_EDGES; i += nthr) atomicAdd(&deg[edst[i]], 1);
}

// ---------------- GEMM1: 32KB B-slab LDS, A direct-f32, 512 threads ---------
__global__ __launch_bounds__(512) void k_gemm1d(const float* __restrict__ X,
                                                const __bf16* __restrict__ Wt,
                                                const float* __restrict__ att_src,
                                                const float* __restrict__ att_dst,
                                                unsigned char* __restrict__ Hf8,
                                                float* __restrict__ a_src1,
                                                float* __restrict__ a_dst1) {
    __shared__ __align__(16) __bf16 Bs[256 * 64];   // 32 KB: 256 cols x 64 K
    int tid = threadIdx.x;
    int wid = tid >> 6, lane = tid & 63;
    int lq = lane >> 4, lm = lane & 15;
    int half = blockIdx.x & 1;             // column half (0: cols 0-255, 1: 256-511)
    int rowt = blockIdx.x >> 1;            // 128-row tile
    int row0 = rowt * 128 + wid * 16;
    int c0 = half * 256;
    int arow = row0 + lm;
    if (arow >= N_NODES) arow = N_NODES - 1;   // clamp (stores are guarded)
    const float* ap = X + (size_t)arow * IN_CH;
    int sw = lm & 7;
    f32x4 acc[16] = {};
    #pragma unroll
    for (int s = 0; s < 4; ++s) {
        if (s) __syncthreads();            // all reads of previous slab done
        #pragma unroll
        for (int it = 0; it < 4; ++it) {
            int idx = it * 512 + tid;      // 0..2047
            int r = idx >> 3;              // B col within half, 0..255
            int p = idx & 7;               // stored chunk position
            gl_lds16(&Wt[(size_t)(c0 + r) * IN_CH + s * 64 + ((p ^ (r & 7)) * 8)],
                     &Bs[idx * 8]);
        }
        // A fragments for this stage's 2 K-steps, f32 direct + convert
        float4 a00 = *(const float4*)&ap[s * 64 + lq * 8];
        float4 a01 = *(const float4*)&ap[s * 64 + lq * 8 + 4];
        float4 a10 = *(const float4*)&ap[s * 64 + 32 + lq * 8];
        float4 a11 = *(const float4*)&ap[s * 64 + 32 + lq * 8 + 4];
        bf16x8 af0 = f32x8_to_bf16x8(a00, a01);
        bf16x8 af1 = f32x8_to_bf16x8(a10, a11);
        __syncthreads();                   // drains vmcnt: slab visible
        #pragma unroll
        for (int kt = 0; kt < 2; ++kt) {
            bf16x8 af = kt ? af1 : af0;
            #pragma unroll
            for (int c = 0; c < 16; ++c) {
                bf16x8 bfr = *(const bf16x8*)&Bs[(c * 16 + lm) * 64 +
                                                 (((kt * 4 + lq) ^ sw) * 8)];
                acc[c] = __builtin_amdgcn_mfma_f32_16x16x32_bf16(af, bfr, acc[c], 0, 0, 0);
            }
        }
    }
    // ---- epilogue: fused att logits + fp8 byte stores ----
    float as_v[16], ad_v[16];
    #pragma unroll
    for (int c = 0; c < 16; ++c) {
        int h = half * 4 + (c >> 2);
        as_v[c] = att_src[h * HID + (c & 3) * 16 + lm];
        ad_v[c] = att_dst[h * HID + (c & 3) * 16 + lm];
    }
    #pragma unroll
    for (int r = 0; r < 4; ++r) {
        int gr = row0 + lq * 4 + r;
        bool ok = gr < N_NODES;
        #pragma unroll
        for (int h = 0; h < 4; ++h) {
            float ps = 0.f, pd = 0.f;
            #pragma unroll
            for (int cc = 0; cc < 4; ++cc) {
                int c = h * 4 + cc;
                float v = acc[c][r];
                ps += v * as_v[c];
                pd += v * ad_v[c];
                if (ok)
                    Hf8[(size_t)gr * D1 + c0 + c * 16 + lm] = f32_to_fp8(v);
            }
            #pragma unroll
            for (int off = 1; off < 16; off <<= 1) {
                ps += __shfl_xor(ps, off);
                pd += __shfl_xor(pd, off);
            }
            if (lm == 0 && ok) {
                a_src1[gr * HEADS + half * 4 + h] = ps;
                a_dst1[gr * HEADS + half * 4 + h] = pd;
            }
        }
    }
}

// ---------------- CSR scan phase 1 ------------------------------------------
__global__ __launch_bounds__(1024) void k_scan1(const int* __restrict__ deg,
                                                int* __restrict__ offsets,
                                                int* __restrict__ bsum) {
    __shared__ int wsum[16];
    int tid = threadIdx.x, lane = tid & 63, wid = tid >> 6;
    int i = blockIdx.x * 1024 + tid;
    int v = (i < N_NODES) ? deg[i] : 0;
    int x = v;
    #pragma unroll
    for (int off = 1; off < 64; off <<= 1) {
        int t = __shfl_up(x, off);
        if (lane >= off) x += t;
    }
    if (lane == 63) wsum[wid] = x;
    __syncthreads();
    if (wid == 0) {
        int s = (lane < 16) ? wsum[lane] : 0;
        #pragma unroll
        for (int off = 1; off < 16; off <<= 1) {
            int t = __shfl_up(s, off);
            if (lane >= off) s += t;
        }
        if (lane < 16) wsum[lane] = s;
    }
    __syncthreads();
    int wbase = wid ? wsum[wid - 1] : 0;
    if (i < N_NODES) offsets[i] = wbase + x - v;
    if (tid == 1023) bsum[blockIdx.x] = wsum[15];
}

// ---------------- scan phase 2+3 fused ---------------------------------------
__global__ __launch_bounds__(256) void k_scan3(int* __restrict__ offsets,
                                               const int* __restrict__ bsum,
                                               int* __restrict__ cursor) {
    __shared__ int bpre_s[64];
    int tid = threadIdx.x;
    const int nb = (N_NODES + 1023) / 1024;   // 49
    if (tid < 64) {
        int v = (tid < nb) ? bsum[tid] : 0;
        int x = v;
        #pragma unroll
        for (int off = 1; off < 64; off <<= 1) {
            int t = __shfl_up(x, off);
            if (tid >= off) x += t;
        }
        bpre_s[tid] = x - v;
        if (blockIdx.x == 0 && tid == nb - 1) offsets[N_NODES] = x;
    }
    __syncthreads();
    int i = blockIdx.x * 256 + tid;
    if (i < N_NODES) {
        int o = offsets[i] + bpre_s[i >> 10];
        offsets[i] = o;
        cursor[i] = o;
    }
}

// ---------------- scatter: pure CSR build (weights recomputed in agg) -------
__global__ void k_scatter(const int* __restrict__ esrc, const int* __restrict__ edst,
                          int* __restrict__ cursor, int* __restrict__ csr) {
    int e = blockIdx.x * blockDim.x + threadIdx.x;
    if (e >= N_EDGES) return;
    int s = esrc[e], d = edst[e];
    int pos = atomicAdd(&cursor[d], 1);
    csr[pos] = s;
}

// ---- agg1 edge-pair body (loads first so the scheduler can hoist) ----------
__device__ inline void agg1_pair(const unsigned char* __restrict__ Hf8,
                                 const float* __restrict__ a_src,
                                 int sA, int sB, int chb, int head, float ad_h,
                                 float* o, float& lsum) {
    uint4 uA = *(const uint4*)&Hf8[(size_t)sA * D1 + chb];
    uint4 uB = *(const uint4*)&Hf8[(size_t)sB * D1 + chb];
    float wA = leaky_exp(a_src[sA * HEADS + head] + ad_h);
    float wB = leaky_exp(a_src[sB * HEADS + head] + ad_h);
    float fA[16], fB[16];
    fp8x16_to_f32(uA, fA);
    fp8x16_to_f32(uB, fB);
    lsum += wA + wB;
    #pragma unroll
    for (int j = 0; j < 16; ++j) o[j] += wA * fA[j] + wB * fB[j];
}

// ---------------- layer-1 aggregation FUSED with layer-2 linear --------------
// R8 established agg1's gather loop is memory-throughput-bound (~55us floor:
// 256MB of L2/L3 gather traffic). This round keeps the proven R7 single-wave
// loop and instead fuses the 512x16 layer-2 linear into the epilogue:
// after the xor(32) combine BOTH halves hold the full post-softmax row, so
// each half computes 8 of the 16 H2 channels (128 FMA/lane + 40-shfl reduce,
// Wt2 is 16KB L1-hot). Eliminates the 51.2MB out1 write, gemm2's 51.2MB
// read, and the gemm2 launch entirely. WRITE_SIZE should drop 50MB -> ~2.5MB.
__global__ __launch_bounds__(256) void k_agg1(const unsigned char* __restrict__ Hf8,
                                              const float* __restrict__ a_src,
                                              const float* __restrict__ a_dst,
                                              const int* __restrict__ offsets,
                                              const int* __restrict__ csr,
                                              const float* __restrict__ b1,
                                              const __bf16* __restrict__ Wt2,
                                              const float* __restrict__ as2,
                                              const float* __restrict__ ad2,
                                              __bf16* __restrict__ H2,
                                              float* __restrict__ a_src2,
                                              float* __restrict__ a_dst2) {
    int wave = (blockIdx.x * blockDim.x + threadIdx.x) >> 6;
    int lane = threadIdx.x & 63;
    if (wave >= N_NODES) return;
    int d = wave;
    int half = lane >> 5;      // edge parity this lane handles
    int l32 = lane & 31;
    int chb = l32 * 16;        // 16 channels per lane
    int head = l32 >> 2;
    float ad_h = a_dst[d * HEADS + head];
    float o[16];
    #pragma unroll
    for (int j = 0; j < 16; ++j) o[j] = 0.f;
    float lsum = 0.f;
    if (half == 0) {           // self-loop handled once
        float wself = leaky_exp(a_src[d * HEADS + head] + ad_h);
        uint4 hu = *(const uint4*)&Hf8[(size_t)d * D1 + chb];
        float hv[16];
        fp8x16_to_f32(hu, hv);
        lsum = wself;
        #pragma unroll
        for (int j = 0; j < 16; ++j) o[j] = wself * hv[j];
    }
    int beg = offsets[d], end = offsets[d + 1];
    int idx = beg;
    if (idx + 4 <= end) {
        int sA = csr[idx + half];
        int sB = csr[idx + 2 + half];
        for (; idx + 8 <= end; idx += 4) {
            int sA2 = csr[idx + 4 + half];      // prefetch next quad's indices
            int sB2 = csr[idx + 6 + half];
            agg1_pair(Hf8, a_src, sA, sB, chb, head, ad_h, o, lsum);
            sA = sA2; sB = sB2;
        }
        agg1_pair(Hf8, a_src, sA, sB, chb, head, ad_h, o, lsum);   // drain
        idx += 4;
    }
    for (; idx < end; idx += 2) {            // tail (validity-masked)
        int e = idx + half;
        bool valid = e < end;
        int s = valid ? csr[e] : csr[idx];
        uint4 u = *(const uint4*)&Hf8[(size_t)s * D1 + chb];
        float w = valid ? leaky_exp(a_src[s * HEADS + head] + ad_h) : 0.f;
        float f[16];
        fp8x16_to_f32(u, f);
        lsum += w;
        #pragma unroll
        for (int j = 0; j < 16; ++j) o[j] += w * f[j];
    }
    // combine edge-parity halves -> BOTH halves hold the full sums
    #pragma unroll
    for (int j = 0; j < 16; ++j) o[j] += __shfl_xor(o[j], 32);
    lsum += __shfl_xor(lsum, 32);
    // finish layer-1 in-register: normalize + bias + ELU (identical per half)
    float inv = 1.0f / (lsum + 1e-16f);
    #pragma unroll
    for (int j = 0; j < 16; ++j) {
        float t = o[j] * inv + b1[chb + j];
        o[j] = t > 0.f ? t : (__expf(t) - 1.0f);   // ELU
    }
    // fused layer-2 linear: half h computes output channels [h*8, h*8+8)
    int cbase = half * 8;
    float p[8];
    #pragma unroll
    for (int c = 0; c < 8; ++c) {
        const __bf16* wrow = &Wt2[(size_t)(cbase + c) * D1 + chb];
        bf16x8 w0 = *(const bf16x8*)&wrow[0];
        bf16x8 w1 = *(const bf16x8*)&wrow[8];
        float acc = 0.f;
        #pragma unroll
        for (int j = 0; j < 8; ++j) acc += o[j] * (float)w0[j];
        #pragma unroll
        for (int j = 0; j < 8; ++j) acc += o[8 + j] * (float)w1[j];
        p[c] = acc;
    }
    // reduce partials over the 32 lanes of this half
    #pragma unroll
    for (int off = 1; off < 32; off <<= 1) {
        #pragma unroll
        for (int c = 0; c < 8; ++c) p[c] += __shfl_xor(p[c], off);
    }
    // layer-2 attention logits: combine the two halves' partial dots
    float asp = 0.f, adp = 0.f;
    #pragma unroll
    for (int c = 0; c < 8; ++c) {
        asp += p[c] * as2[cbase + c];
        adp += p[c] * ad2[cbase + c];
    }
    asp += __shfl_xor(asp, 32);
    adp += __shfl_xor(adp, 32);
    if (l32 == 0) {
        __bf16 hh[8];
        #pragma unroll
        for (int c = 0; c < 8; ++c) hh[c] = (__bf16)p[c];
        *(uint4*)&H2[(size_t)d * OUT_CH + cbase] = *(uint4*)hh;
        if (half == 0) { a_src2[d] = asp; a_dst2[d] = adp; }
    }
}

// ---- agg2 edge-pair body ----------------------------------------------------
__device__ inline void agg2_pair(const __bf16* __restrict__ H2,
                                 const float* __restrict__ a_src,
                                 int s0, int s1, int c, float ad,
                                 float& o, float& lsum) {
    float h0 = (float)H2[s0 * OUT_CH + c];
    float h1 = (float)H2[s1 * OUT_CH + c];
    float wt0 = leaky_exp(a_src[s0] + ad);
    float wt1 = leaky_exp(a_src[s1] + ad);
    lsum += wt0 + wt1;
    o += wt0 * h0 + wt1 * h1;
}

// ---------------- layer-2 aggregation + csr pipeline + log_softmax ----------
__global__ __launch_bounds__(256) void k_agg2(const __bf16* __restrict__ H2,
                                              const float* __restrict__ a_src,
                                              const float* __restrict__ a_dst,
                                              const int* __restrict__ offsets,
                                              const int* __restrict__ csr,
                                              const float* __restrict__ b2,
                                              float* __restrict__ OUT) {
    int wave = (blockIdx.x * blockDim.x + threadIdx.x) >> 6;
    int lane = threadIdx.x & 63;
    if (wave >= N_NODES) return;
    int d = wave;
    int g = lane >> 4, c = lane & 15;
    float ad = a_dst[d];
    float o = 0.f, lsum = 0.f;
    if (g == 0) {
        float wself = leaky_exp(a_src[d] + ad);
        o = wself * (float)H2[d * OUT_CH + c];
        lsum = wself;
    }
    int beg = offsets[d], end = offsets[d + 1];
    int i0 = beg + g;
    if (i0 + 4 < end) {
        int s0 = csr[i0], s1 = csr[i0 + 4];
        for (; i0 + 12 < end; i0 += 8) {
            int t0 = csr[i0 + 8], t1 = csr[i0 + 12];   // prefetch next pair
            agg2_pair(H2, a_src, s0, s1, c, ad, o, lsum);
            s0 = t0; s1 = t1;
        }
        agg2_pair(H2, a_src, s0, s1, c, ad, o, lsum);  // drain
        i0 += 8;
    }
    for (; i0 < end; i0 += 4) {          // tail
        int s = csr[i0];
        float wt = leaky_exp(a_src[s] + ad);
        float h = (float)H2[s * OUT_CH + c];
        lsum += wt;
        o += wt * h;
    }
    o += __shfl_xor(o, 16);  o += __shfl_xor(o, 32);
    lsum += __shfl_xor(lsum, 16);  lsum += __shfl_xor(lsum, 32);
    float v = o / (lsum + 1e-16f) + b2[c];
    float mx = v;
    #pragma unroll
    for (int off = 1; off < 16; off <<= 1) mx = fmaxf(mx, __shfl_xor(mx, off));
    float se = __expf(v - mx);
    #pragma unroll
    for (int off = 1; off < 16; off <<= 1) se += __shfl_xor(se, off);
    float res = v - mx - logf(se);
    if (lane < 16) OUT[d * OUT_CH + lane] = res;
}

// ---------------- launcher --------------------------------------------------
extern "C" void kernel_launch(void* const* d_in, const int* in_sizes, int n_in,
                              void* d_out, int out_size, void* d_ws, size_t ws_size,
                              hipStream_t stream) {
    const float* x        = (const float*)d_in[0];
    const int*   ei       = (const int*)d_in[1];
    const float* W1       = (const float*)d_in[2];
    const float* att_src1 = (const float*)d_in[3];
    const float* att_dst1 = (const float*)d_in[4];
    const float* b1       = (const float*)d_in[5];
    const float* W2       = (const float*)d_in[6];
    const float* att_src2 = (const float*)d_in[7];
    const float* att_dst2 = (const float*)d_in[8];
    const float* b2       = (const float*)d_in[9];
    float* out = (float*)d_out;

    const int* esrc = ei;
    const int* edst = ei + N_EDGES;

    char* ws = (char*)d_ws;
    size_t off = 0;
    auto alloc = [&](size_t bytes) { char* p = ws + off; off = (off + bytes + 255) & ~(size_t)255; return p; };
    unsigned char* Hf8 = (unsigned char*)alloc((size_t)N_NODES * D1); // 25.6 MB
    __bf16* Wt     = (__bf16*)alloc((size_t)D1 * IN_CH * 2);
    __bf16* Wt2    = (__bf16*)alloc((size_t)D1 * OUT_CH * 2);
    float* a_src1  = (float*)alloc((size_t)N_NODES * HEADS * 4);
    float* a_dst1  = (float*)alloc((size_t)N_NODES * HEADS * 4);
    __bf16* h2     = (__bf16*)alloc((size_t)N_NODES * OUT_CH * 2);    // 1.6 MB
    float* a_src2  = (float*)alloc((size_t)N_NODES * 4);
    float* a_dst2  = (float*)alloc((size_t)N_NODES * 4);
    int*   deg     = (int*)alloc((size_t)N_NODES * 4);
    int*   offsets = (int*)alloc((size_t)(N_NODES + 1) * 4);
    int*   cursor  = (int*)alloc((size_t)N_NODES * 4);
    int*   csr     = (int*)alloc((size_t)N_EDGES * 4);
    int*   bsum    = (int*)alloc(64 * 4);
    (void)ws_size;

    // 0. zero deg, then prep (W converts + histogram)
    hipMemsetAsync(deg, 0, (size_t)N_NODES * 4, stream);
    k_prep<<<512, 256, 0, stream>>>(W1, W2, edst, Wt, Wt2, deg);
    // 1. GEMM1 (32KB B-slab LDS, A direct-f32) + att1 logits, fp8 H out
    int g1_blocks = ((N_NODES + 127) / 128) * 2;   // 128-row tiles x 2 col halves
    k_gemm1d<<<g1_blocks, 512, 0, stream>>>(x, Wt, att_src1, att_dst1, Hf8, a_src1, a_dst1);
    // 2. CSR build
    int nb = (N_NODES + 1023) / 1024;
    k_scan1<<<nb, 1024, 0, stream>>>(deg, offsets, bsum);
    k_scan3<<<(N_NODES + 255) / 256, 256, 0, stream>>>(offsets, bsum, cursor);
    k_scatter<<<(N_EDGES + 255) / 256, 256, 0, stream>>>(esrc, edst, cursor, csr);
    // 3. layer-1 aggregation + bias + ELU + FUSED layer-2 linear/logits
    //    (out1 buffer and gemm2 kernel eliminated)
    k_agg1<<<(N_NODES * 64 + 255) / 256, 256, 0, stream>>>(
        Hf8, a_src1, a_dst1, offsets, csr, b1, Wt2, att_src2, att_dst2,
        h2, a_src2, a_dst2);
    // 4. layer-2 aggregation (inline weights) + log_softmax
    k_agg2<<<(N_NODES * 64 + 255) / 256, 256, 0, stream>>>(h2, a_src2, a_dst2, offsets, csr, b2, out);
}

// Round 10
// 279.502 us; speedup vs baseline: 1.0825x; 1.0825x over previous
//
#include <hip/hip_runtime.h>
#include <math.h>

#define N_NODES 50000
#define N_EDGES 500000
#define IN_CH 256
#define D1 512          // HEADS*HID
#define HEADS 8
#define HID 64
#define OUT_CH 16
#define NEG_SLOPE 0.2f

typedef __bf16 bf16x8 __attribute__((ext_vector_type(8)));
typedef float f32x4 __attribute__((ext_vector_type(4)));
typedef float f32x2 __attribute__((ext_vector_type(2)));

// convert 8 packed fp8 e4m3 (uint2) -> 8 floats via HW v_cvt_pk_f32_fp8
__device__ inline void fp8x8_to_f32(uint2 u, float* f) {
    f32x2 p0 = __builtin_amdgcn_cvt_pk_f32_fp8(u.x, false);
    f32x2 p1 = __builtin_amdgcn_cvt_pk_f32_fp8(u.x, true);
    f32x2 p2 = __builtin_amdgcn_cvt_pk_f32_fp8(u.y, false);
    f32x2 p3 = __builtin_amdgcn_cvt_pk_f32_fp8(u.y, true);
    f[0] = p0.x; f[1] = p0.y; f[2] = p1.x; f[3] = p1.y;
    f[4] = p2.x; f[5] = p2.y; f[6] = p3.x; f[7] = p3.y;
}

__device__ inline void fp8x16_to_f32(uint4 u, float* f) {
    fp8x8_to_f32(make_uint2(u.x, u.y), f);
    fp8x8_to_f32(make_uint2(u.z, u.w), f + 8);
}

__device__ inline unsigned char f32_to_fp8(float v) {
    return (unsigned char)(__builtin_amdgcn_cvt_pk_fp8_f32(v, v, 0, false) & 0xff);
}

__device__ inline float leaky_exp(float e) {
    float v = e > 0.f ? e : NEG_SLOPE * e;
    return __expf(v);
}

// async global->LDS, 16B per lane; LDS dest = wave-uniform base + lane*16
__device__ inline void gl_lds16(const __bf16* g, __bf16* l) {
    __builtin_amdgcn_global_load_lds(
        (const __attribute__((address_space(1))) unsigned int*)g,
        (__attribute__((address_space(3))) unsigned int*)l,
        16, 0, 0);
}

// pack 8 floats -> bf16x8
__device__ inline bf16x8 f32x8_to_bf16x8(const float4& a, const float4& b) {
    bf16x8 r;
    r[0] = (__bf16)a.x; r[1] = (__bf16)a.y; r[2] = (__bf16)a.z; r[3] = (__bf16)a.w;
    r[4] = (__bf16)b.x; r[5] = (__bf16)b.y; r[6] = (__bf16)b.z; r[7] = (__bf16)b.w;
    return r;
}

// ---------------- prep: W converts + edge histogram (deg pre-zeroed) --------
__global__ __launch_bounds__(256) void k_prep(const float* __restrict__ W1,
                                              const float* __restrict__ W2,
                                              const int* __restrict__ edst,
                                              __bf16* __restrict__ Wt,
                                              __bf16* __restrict__ Wt2,
                                              int* __restrict__ deg) {
    int t = blockIdx.x * 256 + threadIdx.x;
    int nthr = gridDim.x * 256;
    for (int i = t; i < D1 * IN_CH; i += nthr) {
        int n = i >> 8, k = i & 255;
        Wt[i] = (__bf16)W1[k * D1 + n];
    }
    for (int i = t; i < D1 * OUT_CH; i += nthr) {
        int n = i >> 9, k = i & 511;
        Wt2[i] = (__bf16)W2[k * OUT_CH + n];
    }
    for (int i = t; i < N_EDGES; i += nthr) atomicAdd(&deg[edst[i]], 1);
}

// ---------------- GEMM1: 32KB B-slab LDS, A direct-f32, 512 threads ---------
__global__ __launch_bounds__(512) void k_gemm1d(const float* __restrict__ X,
                                                const __bf16* __restrict__ Wt,
                                                const float* __restrict__ att_src,
                                                const float* __restrict__ att_dst,
                                                unsigned char* __restrict__ Hf8,
                                                float* __restrict__ a_src1,
                                                float* __restrict__ a_dst1) {
    __shared__ __align__(16) __bf16 Bs[256 * 64];   // 32 KB: 256 cols x 64 K
    int tid = threadIdx.x;
    int wid = tid >> 6, lane = tid & 63;
    int lq = lane >> 4, lm = lane & 15;
    int half = blockIdx.x & 1;             // column half (0: cols 0-255, 1: 256-511)
    int rowt = blockIdx.x >> 1;            // 128-row tile
    int row0 = rowt * 128 + wid * 16;
    int c0 = half * 256;
    int arow = row0 + lm;
    if (arow >= N_NODES) arow = N_NODES - 1;   // clamp (stores are guarded)
    const float* ap = X + (size_t)arow * IN_CH;
    int sw = lm & 7;
    f32x4 acc[16] = {};
    #pragma unroll
    for (int s = 0; s < 4; ++s) {
        if (s) __syncthreads();            // all reads of previous slab done
        #pragma unroll
        for (int it = 0; it < 4; ++it) {
            int idx = it * 512 + tid;      // 0..2047
            int r = idx >> 3;              // B col within half, 0..255
            int p = idx & 7;               // stored chunk position
            gl_lds16(&Wt[(size_t)(c0 + r) * IN_CH + s * 64 + ((p ^ (r & 7)) * 8)],
                     &Bs[idx * 8]);
        }
        // A fragments for this stage's 2 K-steps, f32 direct + convert
        float4 a00 = *(const float4*)&ap[s * 64 + lq * 8];
        float4 a01 = *(const float4*)&ap[s * 64 + lq * 8 + 4];
        float4 a10 = *(const float4*)&ap[s * 64 + 32 + lq * 8];
        float4 a11 = *(const float4*)&ap[s * 64 + 32 + lq * 8 + 4];
        bf16x8 af0 = f32x8_to_bf16x8(a00, a01);
        bf16x8 af1 = f32x8_to_bf16x8(a10, a11);
        __syncthreads();                   // drains vmcnt: slab visible
        #pragma unroll
        for (int kt = 0; kt < 2; ++kt) {
            bf16x8 af = kt ? af1 : af0;
            #pragma unroll
            for (int c = 0; c < 16; ++c) {
                bf16x8 bfr = *(const bf16x8*)&Bs[(c * 16 + lm) * 64 +
                                                 (((kt * 4 + lq) ^ sw) * 8)];
                acc[c] = __builtin_amdgcn_mfma_f32_16x16x32_bf16(af, bfr, acc[c], 0, 0, 0);
            }
        }
    }
    // ---- epilogue: fused att logits + fp8 byte stores ----
    float as_v[16], ad_v[16];
    #pragma unroll
    for (int c = 0; c < 16; ++c) {
        int h = half * 4 + (c >> 2);
        as_v[c] = att_src[h * HID + (c & 3) * 16 + lm];
        ad_v[c] = att_dst[h * HID + (c & 3) * 16 + lm];
    }
    #pragma unroll
    for (int r = 0; r < 4; ++r) {
        int gr = row0 + lq * 4 + r;
        bool ok = gr < N_NODES;
        #pragma unroll
        for (int h = 0; h < 4; ++h) {
            float ps = 0.f, pd = 0.f;
            #pragma unroll
            for (int cc = 0; cc < 4; ++cc) {
                int c = h * 4 + cc;
                float v = acc[c][r];
                ps += v * as_v[c];
                pd += v * ad_v[c];
                if (ok)
                    Hf8[(size_t)gr * D1 + c0 + c * 16 + lm] = f32_to_fp8(v);
            }
            #pragma unroll
            for (int off = 1; off < 16; off <<= 1) {
                ps += __shfl_xor(ps, off);
                pd += __shfl_xor(pd, off);
            }
            if (lm == 0 && ok) {
                a_src1[gr * HEADS + half * 4 + h] = ps;
                a_dst1[gr * HEADS + half * 4 + h] = pd;
            }
        }
    }
}

// ---------------- CSR range allocation: one kernel, atomic base -------------
// Replaces scan1+scan3: block-local inclusive scan (1024 threads) + ONE
// atomicAdd on a global counter per block (49 atomics total) allocates each
// block's contiguous CSR range. Node ranges come out in arbitrary order --
// agg kernels only need [beg, beg+deg) per node, so ordering is irrelevant.
__global__ __launch_bounds__(1024) void k_csr(const int* __restrict__ deg,
                                              int* __restrict__ counter,
                                              int* __restrict__ offsets,
                                              int* __restrict__ cursor) {
    __shared__ int wsum[16];
    __shared__ int base_s;
    int tid = threadIdx.x, lane = tid & 63, wid = tid >> 6;
    int i = blockIdx.x * 1024 + tid;
    int v = (i < N_NODES) ? deg[i] : 0;
    int x = v;
    #pragma unroll
    for (int off = 1; off < 64; off <<= 1) {
        int t = __shfl_up(x, off);
        if (lane >= off) x += t;
    }
    if (lane == 63) wsum[wid] = x;
    __syncthreads();
    if (wid == 0) {
        int s = (lane < 16) ? wsum[lane] : 0;
        #pragma unroll
        for (int off = 1; off < 16; off <<= 1) {
            int t = __shfl_up(s, off);
            if (lane >= off) s += t;
        }
        if (lane < 16) wsum[lane] = s;
    }
    __syncthreads();
    if (tid == 0) base_s = atomicAdd(counter, wsum[15]);
    __syncthreads();
    int wbase = wid ? wsum[wid - 1] : 0;
    if (i < N_NODES) {
        int o = base_s + wbase + x - v;
        offsets[i] = o;
        cursor[i] = o;
    }
}

// ---------------- scatter: pure CSR build (weights recomputed in agg) -------
__global__ void k_scatter(const int* __restrict__ esrc, const int* __restrict__ edst,
                          int* __restrict__ cursor, int* __restrict__ csr) {
    int e = blockIdx.x * blockDim.x + threadIdx.x;
    if (e >= N_EDGES) return;
    int s = esrc[e], d = edst[e];
    int pos = atomicAdd(&cursor[d], 1);
    csr[pos] = s;
}

// ---- agg1 edge-pair body (loads first so the scheduler can hoist) ----------
__device__ inline void agg1_pair(const unsigned char* __restrict__ Hf8,
                                 const float* __restrict__ a_src,
                                 int sA, int sB, int chb, int head, float ad_h,
                                 float* o, float& lsum) {
    uint4 uA = *(const uint4*)&Hf8[(size_t)sA * D1 + chb];
    uint4 uB = *(const uint4*)&Hf8[(size_t)sB * D1 + chb];
    float wA = leaky_exp(a_src[sA * HEADS + head] + ad_h);
    float wB = leaky_exp(a_src[sB * HEADS + head] + ad_h);
    float fA[16], fB[16];
    fp8x16_to_f32(uA, fA);
    fp8x16_to_f32(uB, fB);
    lsum += wA + wB;
    #pragma unroll
    for (int j = 0; j < 16; ++j) o[j] += wA * fA[j] + wB * fB[j];
}

// ---------------- layer-1 aggregation: pair-edge + csr index pipeline -------
// R7-proven form (55.5us, VGPR 36, occ 57%). R8/R9 established this is the
// floor: 2-wave split (+12us), deeper unroll (VGPR->occupancy loss), and
// gemm2 fusion (VGPR 60 -> occ 38%, gather BW 3.6->1.5 TB/s) all regress.
// Range is [beg, beg+deg[d]) -- CSR ranges are unordered (k_csr atomic base).
__global__ __launch_bounds__(256) void k_agg1(const unsigned char* __restrict__ Hf8,
                                              const float* __restrict__ a_src,
                                              const float* __restrict__ a_dst,
                                              const int* __restrict__ offsets,
                                              const int* __restrict__ deg,
                                              const int* __restrict__ csr,
                                              const float* __restrict__ b1,
                                              __bf16* __restrict__ OUT) {
    int wave = (blockIdx.x * blockDim.x + threadIdx.x) >> 6;
    int lane = threadIdx.x & 63;
    if (wave >= N_NODES) return;
    int d = wave;
    int half = lane >> 5;      // edge parity this lane handles
    int l32 = lane & 31;
    int chb = l32 * 16;        // 16 channels per lane
    int head = l32 >> 2;
    float ad_h = a_dst[d * HEADS + head];
    float o[16];
    #pragma unroll
    for (int j = 0; j < 16; ++j) o[j] = 0.f;
    float lsum = 0.f;
    if (half == 0) {           // self-loop handled once
        float wself = leaky_exp(a_src[d * HEADS + head] + ad_h);
        uint4 hu = *(const uint4*)&Hf8[(size_t)d * D1 + chb];
        float hv[16];
        fp8x16_to_f32(hu, hv);
        lsum = wself;
        #pragma unroll
        for (int j = 0; j < 16; ++j) o[j] = wself * hv[j];
    }
    int beg = offsets[d], end = beg + deg[d];
    int idx = beg;
    if (idx + 4 <= end) {
        int sA = csr[idx + half];
        int sB = csr[idx + 2 + half];
        for (; idx + 8 <= end; idx += 4) {
            int sA2 = csr[idx + 4 + half];      // prefetch next quad's indices
            int sB2 = csr[idx + 6 + half];
            agg1_pair(Hf8, a_src, sA, sB, chb, head, ad_h, o, lsum);
            sA = sA2; sB = sB2;
        }
        agg1_pair(Hf8, a_src, sA, sB, chb, head, ad_h, o, lsum);   // drain
        idx += 4;
    }
    for (; idx < end; idx += 2) {            // tail (validity-masked)
        int e = idx + half;
        bool valid = e < end;
        int s = valid ? csr[e] : csr[idx];
        uint4 u = *(const uint4*)&Hf8[(size_t)s * D1 + chb];
        float w = valid ? leaky_exp(a_src[s * HEADS + head] + ad_h) : 0.f;
        float f[16];
        fp8x16_to_f32(u, f);
        lsum += w;
        #pragma unroll
        for (int j = 0; j < 16; ++j) o[j] += w * f[j];
    }
    // combine edge-parity halves
    #pragma unroll
    for (int j = 0; j < 16; ++j) o[j] += __shfl_xor(o[j], 32);
    lsum += __shfl_xor(lsum, 32);
    if (half == 0) {
        float inv = 1.0f / (lsum + 1e-16f);
        __bf16 r[16];
        #pragma unroll
        for (int j = 0; j < 16; ++j) {
            float v = o[j] * inv + b1[chb + j];
            v = v > 0.f ? v : (__expf(v) - 1.0f);   // ELU (cheap form)
            r[j] = (__bf16)v;
        }
        *(uint4*)&OUT[(size_t)d * D1 + chb]     = *(uint4*)&r[0];
        *(uint4*)&OUT[(size_t)d * D1 + chb + 8] = *(uint4*)&r[8];
    }
}

// ---------------- GEMM2 (MFMA, no LDS) + layer-2 logits, bf16 H2 ------------
__global__ __launch_bounds__(256) void k_gemm2_mfma(const __bf16* __restrict__ A,
                                                    const __bf16* __restrict__ Wt2,
                                                    const float* __restrict__ as2v,
                                                    const float* __restrict__ ad2v,
                                                    __bf16* __restrict__ H2,
                                                    float* __restrict__ a_src2,
                                                    float* __restrict__ a_dst2) {
    int tid = threadIdx.x;
    int wid = tid >> 6, lane = tid & 63;
    int lq = lane >> 4, lm = lane & 15;
    int row0 = blockIdx.x * 64 + wid * 16;
    int arow = row0 + lm;
    const __bf16* ap = A + (size_t)(arow < N_NODES ? arow : 0) * D1;
    f32x4 acc = {};
    #pragma unroll
    for (int k0 = 0; k0 < 16; ++k0) {
        bf16x8 af  = *(const bf16x8*)&ap[k0 * 32 + lq * 8];
        bf16x8 bfr = *(const bf16x8*)&Wt2[lm * D1 + k0 * 32 + lq * 8];
        acc = __builtin_amdgcn_mfma_f32_16x16x32_bf16(af, bfr, acc, 0, 0, 0);
    }
    float as_c = as2v[lm], ad_c = ad2v[lm];
    #pragma unroll
    for (int r = 0; r < 4; ++r) {
        int gr = row0 + lq * 4 + r;
        float v = acc[r];
        if (gr < N_NODES) H2[gr * OUT_CH + lm] = (__bf16)v;
        float ps = v * as_c, pd = v * ad_c;
        #pragma unroll
        for (int off = 1; off < 16; off <<= 1) {
            ps += __shfl_xor(ps, off);
            pd += __shfl_xor(pd, off);
        }
        if (lm == 0 && gr < N_NODES) { a_src2[gr] = ps; a_dst2[gr] = pd; }
    }
}

// ---- agg2 edge-pair body ----------------------------------------------------
__device__ inline void agg2_pair(const __bf16* __restrict__ H2,
                                 const float* __restrict__ a_src,
                                 int s0, int s1, int c, float ad,
                                 float& o, float& lsum) {
    float h0 = (float)H2[s0 * OUT_CH + c];
    float h1 = (float)H2[s1 * OUT_CH + c];
    float wt0 = leaky_exp(a_src[s0] + ad);
    float wt1 = leaky_exp(a_src[s1] + ad);
    lsum += wt0 + wt1;
    o += wt0 * h0 + wt1 * h1;
}

// ---------------- layer-2 aggregation + csr pipeline + log_softmax ----------
__global__ __launch_bounds__(256) void k_agg2(const __bf16* __restrict__ H2,
                                              const float* __restrict__ a_src,
                                              const float* __restrict__ a_dst,
                                              const int* __restrict__ offsets,
                                              const int* __restrict__ deg,
                                              const int* __restrict__ csr,
                                              const float* __restrict__ b2,
                                              float* __restrict__ OUT) {
    int wave = (blockIdx.x * blockDim.x + threadIdx.x) >> 6;
    int lane = threadIdx.x & 63;
    if (wave >= N_NODES) return;
    int d = wave;
    int g = lane >> 4, c = lane & 15;
    float ad = a_dst[d];
    float o = 0.f, lsum = 0.f;
    if (g == 0) {
        float wself = leaky_exp(a_src[d] + ad);
        o = wself * (float)H2[d * OUT_CH + c];
        lsum = wself;
    }
    int beg = offsets[d], end = beg + deg[d];
    int i0 = beg + g;
    if (i0 + 4 < end) {
        int s0 = csr[i0], s1 = csr[i0 + 4];
        for (; i0 + 12 < end; i0 += 8) {
            int t0 = csr[i0 + 8], t1 = csr[i0 + 12];   // prefetch next pair
            agg2_pair(H2, a_src, s0, s1, c, ad, o, lsum);
            s0 = t0; s1 = t1;
        }
        agg2_pair(H2, a_src, s0, s1, c, ad, o, lsum);  // drain
        i0 += 8;
    }
    for (; i0 < end; i0 += 4) {          // tail
        int s = csr[i0];
        float wt = leaky_exp(a_src[s] + ad);
        float h = (float)H2[s * OUT_CH + c];
        lsum += wt;
        o += wt * h;
    }
    o += __shfl_xor(o, 16);  o += __shfl_xor(o, 32);
    lsum += __shfl_xor(lsum, 16);  lsum += __shfl_xor(lsum, 32);
    float v = o / (lsum + 1e-16f) + b2[c];
    float mx = v;
    #pragma unroll
    for (int off = 1; off < 16; off <<= 1) mx = fmaxf(mx, __shfl_xor(mx, off));
    float se = __expf(v - mx);
    #pragma unroll
    for (int off = 1; off < 16; off <<= 1) se += __shfl_xor(se, off);
    float res = v - mx - logf(se);
    if (lane < 16) OUT[d * OUT_CH + lane] = res;
}

// ---------------- launcher --------------------------------------------------
extern "C" void kernel_launch(void* const* d_in, const int* in_sizes, int n_in,
                              void* d_out, int out_size, void* d_ws, size_t ws_size,
                              hipStream_t stream) {
    const float* x        = (const float*)d_in[0];
    const int*   ei       = (const int*)d_in[1];
    const float* W1       = (const float*)d_in[2];
    const float* att_src1 = (const float*)d_in[3];
    const float* att_dst1 = (const float*)d_in[4];
    const float* b1       = (const float*)d_in[5];
    const float* W2       = (const float*)d_in[6];
    const float* att_src2 = (const float*)d_in[7];
    const float* att_dst2 = (const float*)d_in[8];
    const float* b2       = (const float*)d_in[9];
    float* out = (float*)d_out;

    const int* esrc = ei;
    const int* edst = ei + N_EDGES;

    char* ws = (char*)d_ws;
    size_t off = 0;
    auto alloc = [&](size_t bytes) { char* p = ws + off; off = (off + bytes + 255) & ~(size_t)255; return p; };
    unsigned char* Hf8 = (unsigned char*)alloc((size_t)N_NODES * D1); // 25.6 MB
    __bf16* out1   = (__bf16*)alloc((size_t)N_NODES * D1 * 2);        // 51.2 MB
    __bf16* Wt     = (__bf16*)alloc((size_t)D1 * IN_CH * 2);
    __bf16* Wt2    = (__bf16*)alloc((size_t)D1 * OUT_CH * 2);
    float* a_src1  = (float*)alloc((size_t)N_NODES * HEADS * 4);
    float* a_dst1  = (float*)alloc((size_t)N_NODES * HEADS * 4);
    __bf16* h2     = (__bf16*)alloc((size_t)N_NODES * OUT_CH * 2);    // 1.6 MB
    float* a_src2  = (float*)alloc((size_t)N_NODES * 4);
    float* a_dst2  = (float*)alloc((size_t)N_NODES * 4);
    int*   deg     = (int*)alloc((size_t)N_NODES * 4 + 256);          // +counter
    int*   counter = deg + N_NODES;
    int*   offsets = (int*)alloc((size_t)(N_NODES + 1) * 4);
    int*   cursor  = (int*)alloc((size_t)N_NODES * 4);
    int*   csr     = (int*)alloc((size_t)N_EDGES * 4);
    (void)ws_size;

    // 0. zero deg + counter, then prep (W converts + histogram)
    hipMemsetAsync(deg, 0, (size_t)N_NODES * 4 + 4, stream);
    k_prep<<<512, 256, 0, stream>>>(W1, W2, edst, Wt, Wt2, deg);
    // 1. GEMM1 (32KB B-slab LDS, A direct-f32) + att1 logits, fp8 H out
    int g1_blocks = ((N_NODES + 127) / 128) * 2;   // 128-row tiles x 2 col halves
    k_gemm1d<<<g1_blocks, 512, 0, stream>>>(x, Wt, att_src1, att_dst1, Hf8, a_src1, a_dst1);
    // 2. CSR build: single-kernel range allocation + scatter
    int nb = (N_NODES + 1023) / 1024;
    k_csr<<<nb, 1024, 0, stream>>>(deg, counter, offsets, cursor);
    k_scatter<<<(N_EDGES + 255) / 256, 256, 0, stream>>>(esrc, edst, cursor, csr);
    // 3. layer-1 aggregation (+bias+ELU), pair-edge gather + index pipeline
    k_agg1<<<(N_NODES * 64 + 255) / 256, 256, 0, stream>>>(Hf8, a_src1, a_dst1,
                                                           offsets, deg, csr, b1, out1);
    // 4. GEMM2 (MFMA) + layer-2 logits, bf16 H2
    k_gemm2_mfma<<<(N_NODES + 63) / 64, 256, 0, stream>>>(out1, Wt2, att_src2, att_dst2, h2, a_src2, a_dst2);
    // 5. layer-2 aggregation (inline weights) + log_softmax
    k_agg2<<<(N_NODES * 64 + 255) / 256, 256, 0, stream>>>(h2, a_src2, a_dst2,
                                                           offsets, deg, csr, b2, out);
}

// Round 12
// 261.640 us; speedup vs baseline: 1.1564x; 1.0683x over previous
//
#include <hip/hip_runtime.h>
#include <math.h>

#define N_NODES 50000
#define N_EDGES 500000
#define IN_CH 256
#define D1 512          // HEADS*HID
#define HEADS 8
#define HID 64
#define OUT_CH 16
#define NEG_SLOPE 0.2f

// gemm1e fused-launch geometry: 782 GEMM blocks + 489 histogram blocks
#define G1B  (((N_NODES + 127) / 128) * 2)   // 782
#define HISTB 489

typedef __bf16 bf16x8 __attribute__((ext_vector_type(8)));
typedef float f32x4 __attribute__((ext_vector_type(4)));
typedef float f32x2 __attribute__((ext_vector_type(2)));

// convert 8 packed fp8 e4m3 (uint2) -> 8 floats via HW v_cvt_pk_f32_fp8
__device__ inline void fp8x8_to_f32(uint2 u, float* f) {
    f32x2 p0 = __builtin_amdgcn_cvt_pk_f32_fp8(u.x, false);
    f32x2 p1 = __builtin_amdgcn_cvt_pk_f32_fp8(u.x, true);
    f32x2 p2 = __builtin_amdgcn_cvt_pk_f32_fp8(u.y, false);
    f32x2 p3 = __builtin_amdgcn_cvt_pk_f32_fp8(u.y, true);
    f[0] = p0.x; f[1] = p0.y; f[2] = p1.x; f[3] = p1.y;
    f[4] = p2.x; f[5] = p2.y; f[6] = p3.x; f[7] = p3.y;
}

__device__ inline void fp8x16_to_f32(uint4 u, float* f) {
    fp8x8_to_f32(make_uint2(u.x, u.y), f);
    fp8x8_to_f32(make_uint2(u.z, u.w), f + 8);
}

__device__ inline unsigned char f32_to_fp8(float v) {
    return (unsigned char)(__builtin_amdgcn_cvt_pk_fp8_f32(v, v, 0, false) & 0xff);
}

__device__ inline float leaky_exp(float e) {
    float v = e > 0.f ? e : NEG_SLOPE * e;
    return __expf(v);
}

// async global->LDS, 16B per lane; LDS dest = wave-uniform base + lane*16
__device__ inline void gl_lds16(const __bf16* g, __bf16* l) {
    __builtin_amdgcn_global_load_lds(
        (const __attribute__((address_space(1))) unsigned int*)g,
        (__attribute__((address_space(3))) unsigned int*)l,
        16, 0, 0);
}

// pack 8 floats -> bf16x8
__device__ inline bf16x8 f32x8_to_bf16x8(const float4& a, const float4& b) {
    bf16x8 r;
    r[0] = (__bf16)a.x; r[1] = (__bf16)a.y; r[2] = (__bf16)a.z; r[3] = (__bf16)a.w;
    r[4] = (__bf16)b.x; r[5] = (__bf16)b.y; r[6] = (__bf16)b.z; r[7] = (__bf16)b.w;
    return r;
}

// ---------------- prep: W converts + zero deg/counter (memset eliminated) ---
__global__ __launch_bounds__(256) void k_prep(const float* __restrict__ W1,
                                              const float* __restrict__ W2,
                                              __bf16* __restrict__ Wt,
                                              __bf16* __restrict__ Wt2,
                                              int* __restrict__ deg,
                                              int* __restrict__ counter) {
    int t = blockIdx.x * 256 + threadIdx.x;
    int nthr = gridDim.x * 256;
    for (int i = t; i < D1 * IN_CH; i += nthr) {
        int n = i >> 8, k = i & 255;
        Wt[i] = (__bf16)W1[k * D1 + n];
    }
    for (int i = t; i < D1 * OUT_CH; i += nthr) {
        int n = i >> 9, k = i & 511;
        Wt2[i] = (__bf16)W2[k * OUT_CH + n];
    }
    for (int i = t; i < N_NODES; i += nthr) deg[i] = 0;
    if (t == 0) *counter = 0;
}

// ---------------- GEMM1 (32KB B-slab LDS, A direct-f32) + histogram range ---
// Blocks [0, G1B): the R7-proven gemm1d body. Blocks [G1B, G1B+HISTB): the
// edge-degree histogram (500K 8B reads + 1 atomic each, ~8-10us of work)
// rides in CU holes / tail of the ~50us GEMM window. Unlike R4's failed
// scatter fusion (heavy payload), this payload is tiny.
__global__ __launch_bounds__(512) void k_gemm1e(const float* __restrict__ X,
                                                const __bf16* __restrict__ Wt,
                                                const float* __restrict__ att_src,
                                                const float* __restrict__ att_dst,
                                                unsigned char* __restrict__ Hf8,
                                                float* __restrict__ a_src1,
                                                float* __restrict__ a_dst1,
                                                const int* __restrict__ edst,
                                                int* __restrict__ deg) {
    __shared__ __align__(16) __bf16 Bs[256 * 64];   // 32 KB: 256 cols x 64 K
    if (blockIdx.x >= G1B) {                        // ---- histogram part ----
        int t = (blockIdx.x - G1B) * 512 + threadIdx.x;
        int nthr = HISTB * 512;
        for (int i = t; i < N_EDGES; i += nthr) atomicAdd(&deg[edst[i]], 1);
        return;
    }
    // ---- GEMM part (byte-identical to R7/R10 k_gemm1d) ----
    int tid = threadIdx.x;
    int wid = tid >> 6, lane = tid & 63;
    int lq = lane >> 4, lm = lane & 15;
    int half = blockIdx.x & 1;             // column half (0: cols 0-255, 1: 256-511)
    int rowt = blockIdx.x >> 1;            // 128-row tile
    int row0 = rowt * 128 + wid * 16;
    int c0 = half * 256;
    int arow = row0 + lm;
    if (arow >= N_NODES) arow = N_NODES - 1;   // clamp (stores are guarded)
    const float* ap = X + (size_t)arow * IN_CH;
    int sw = lm & 7;
    f32x4 acc[16] = {};
    #pragma unroll
    for (int s = 0; s < 4; ++s) {
        if (s) __syncthreads();            // all reads of previous slab done
        #pragma unroll
        for (int it = 0; it < 4; ++it) {
            int idx = it * 512 + tid;      // 0..2047
            int r = idx >> 3;              // B col within half, 0..255
            int p = idx & 7;               // stored chunk position
            gl_lds16(&Wt[(size_t)(c0 + r) * IN_CH + s * 64 + ((p ^ (r & 7)) * 8)],
                     &Bs[idx * 8]);
        }
        // A fragments for this stage's 2 K-steps, f32 direct + convert
        float4 a00 = *(const float4*)&ap[s * 64 + lq * 8];
        float4 a01 = *(const float4*)&ap[s * 64 + lq * 8 + 4];
        float4 a10 = *(const float4*)&ap[s * 64 + 32 + lq * 8];
        float4 a11 = *(const float4*)&ap[s * 64 + 32 + lq * 8 + 4];
        bf16x8 af0 = f32x8_to_bf16x8(a00, a01);
        bf16x8 af1 = f32x8_to_bf16x8(a10, a11);
        __syncthreads();                   // drains vmcnt: slab visible
        #pragma unroll
        for (int kt = 0; kt < 2; ++kt) {
            bf16x8 af = kt ? af1 : af0;
            #pragma unroll
            for (int c = 0; c < 16; ++c) {
                bf16x8 bfr = *(const bf16x8*)&Bs[(c * 16 + lm) * 64 +
                                                 (((kt * 4 + lq) ^ sw) * 8)];
                acc[c] = __builtin_amdgcn_mfma_f32_16x16x32_bf16(af, bfr, acc[c], 0, 0, 0);
            }
        }
    }
    // ---- epilogue: fused att logits + fp8 byte stores ----
    float as_v[16], ad_v[16];
    #pragma unroll
    for (int c = 0; c < 16; ++c) {
        int h = half * 4 + (c >> 2);
        as_v[c] = att_src[h * HID + (c & 3) * 16 + lm];
        ad_v[c] = att_dst[h * HID + (c & 3) * 16 + lm];
    }
    #pragma unroll
    for (int r = 0; r < 4; ++r) {
        int gr = row0 + lq * 4 + r;
        bool ok = gr < N_NODES;
        #pragma unroll
        for (int h = 0; h < 4; ++h) {
            float ps = 0.f, pd = 0.f;
            #pragma unroll
            for (int cc = 0; cc < 4; ++cc) {
                int c = h * 4 + cc;
                float v = acc[c][r];
                ps += v * as_v[c];
                pd += v * ad_v[c];
                if (ok)
                    Hf8[(size_t)gr * D1 + c0 + c * 16 + lm] = f32_to_fp8(v);
            }
            #pragma unroll
            for (int off = 1; off < 16; off <<= 1) {
                ps += __shfl_xor(ps, off);
                pd += __shfl_xor(pd, off);
            }
            if (lm == 0 && ok) {
                a_src1[gr * HEADS + half * 4 + h] = ps;
                a_dst1[gr * HEADS + half * 4 + h] = pd;
            }
        }
    }
}

// ---------------- CSR range allocation: one kernel, atomic base -------------
__global__ __launch_bounds__(1024) void k_csr(const int* __restrict__ deg,
                                              int* __restrict__ counter,
                                              int* __restrict__ offsets,
                                              int* __restrict__ cursor) {
    __shared__ int wsum[16];
    __shared__ int base_s;
    int tid = threadIdx.x, lane = tid & 63, wid = tid >> 6;
    int i = blockIdx.x * 1024 + tid;
    int v = (i < N_NODES) ? deg[i] : 0;
    int x = v;
    #pragma unroll
    for (int off = 1; off < 64; off <<= 1) {
        int t = __shfl_up(x, off);
        if (lane >= off) x += t;
    }
    if (lane == 63) wsum[wid] = x;
    __syncthreads();
    if (wid == 0) {
        int s = (lane < 16) ? wsum[lane] : 0;
        #pragma unroll
        for (int off = 1; off < 16; off <<= 1) {
            int t = __shfl_up(s, off);
            if (lane >= off) s += t;
        }
        if (lane < 16) wsum[lane] = s;
    }
    __syncthreads();
    if (tid == 0) base_s = atomicAdd(counter, wsum[15]);
    __syncthreads();
    int wbase = wid ? wsum[wid - 1] : 0;
    if (i < N_NODES) {
        int o = base_s + wbase + x - v;
        offsets[i] = o;
        cursor[i] = o;
    }
}

// ---------------- scatter: pure CSR build (weights recomputed in agg) -------
__global__ void k_scatter(const int* __restrict__ esrc, const int* __restrict__ edst,
                          int* __restrict__ cursor, int* __restrict__ csr) {
    int e = blockIdx.x * blockDim.x + threadIdx.x;
    if (e >= N_EDGES) return;
    int s = esrc[e], d = edst[e];
    int pos = atomicAdd(&cursor[d], 1);
    csr[pos] = s;
}

// ---- agg1 edge-pair body (loads first so the scheduler can hoist) ----------
__device__ inline void agg1_pair(const unsigned char* __restrict__ Hf8,
                                 const float* __restrict__ a_src,
                                 int sA, int sB, int chb, int head, float ad_h,
                                 float* o, float& lsum) {
    uint4 uA = *(const uint4*)&Hf8[(size_t)sA * D1 + chb];
    uint4 uB = *(const uint4*)&Hf8[(size_t)sB * D1 + chb];
    float wA = leaky_exp(a_src[sA * HEADS + head] + ad_h);
    float wB = leaky_exp(a_src[sB * HEADS + head] + ad_h);
    float fA[16], fB[16];
    fp8x16_to_f32(uA, fA);
    fp8x16_to_f32(uB, fB);
    lsum += wA + wB;
    #pragma unroll
    for (int j = 0; j < 16; ++j) o[j] += wA * fA[j] + wB * fB[j];
}

// ---------------- layer-1 aggregation: pair-edge + csr index pipeline -------
// R7-proven floor form (55us): memory-throughput-bound at full occupancy.
__global__ __launch_bounds__(256) void k_agg1(const unsigned char* __restrict__ Hf8,
                                              const float* __restrict__ a_src,
                                              const float* __restrict__ a_dst,
                                              const int* __restrict__ offsets,
                                              const int* __restrict__ deg,
                                              const int* __restrict__ csr,
                                              const float* __restrict__ b1,
                                              __bf16* __restrict__ OUT) {
    int wave = (blockIdx.x * blockDim.x + threadIdx.x) >> 6;
    int lane = threadIdx.x & 63;
    if (wave >= N_NODES) return;
    int d = wave;
    int half = lane >> 5;      // edge parity this lane handles
    int l32 = lane & 31;
    int chb = l32 * 16;        // 16 channels per lane
    int head = l32 >> 2;
    float ad_h = a_dst[d * HEADS + head];
    float o[16];
    #pragma unroll
    for (int j = 0; j < 16; ++j) o[j] = 0.f;
    float lsum = 0.f;
    if (half == 0) {           // self-loop handled once
        float wself = leaky_exp(a_src[d * HEADS + head] + ad_h);
        uint4 hu = *(const uint4*)&Hf8[(size_t)d * D1 + chb];
        float hv[16];
        fp8x16_to_f32(hu, hv);
        lsum = wself;
        #pragma unroll
        for (int j = 0; j < 16; ++j) o[j] = wself * hv[j];
    }
    int beg = offsets[d], end = beg + deg[d];
    int idx = beg;
    if (idx + 4 <= end) {
        int sA = csr[idx + half];
        int sB = csr[idx + 2 + half];
        for (; idx + 8 <= end; idx += 4) {
            int sA2 = csr[idx + 4 + half];      // prefetch next quad's indices
            int sB2 = csr[idx + 6 + half];
            agg1_pair(Hf8, a_src, sA, sB, chb, head, ad_h, o, lsum);
            sA = sA2; sB = sB2;
        }
        agg1_pair(Hf8, a_src, sA, sB, chb, head, ad_h, o, lsum);   // drain
        idx += 4;
    }
    for (; idx < end; idx += 2) {            // tail (validity-masked)
        int e = idx + half;
        bool valid = e < end;
        int s = valid ? csr[e] : csr[idx];
        uint4 u = *(const uint4*)&Hf8[(size_t)s * D1 + chb];
        float w = valid ? leaky_exp(a_src[s * HEADS + head] + ad_h) : 0.f;
        float f[16];
        fp8x16_to_f32(u, f);
        lsum += w;
        #pragma unroll
        for (int j = 0; j < 16; ++j) o[j] += w * f[j];
    }
    // combine edge-parity halves
    #pragma unroll
    for (int j = 0; j < 16; ++j) o[j] += __shfl_xor(o[j], 32);
    lsum += __shfl_xor(lsum, 32);
    if (half == 0) {
        float inv = 1.0f / (lsum + 1e-16f);
        __bf16 r[16];
        #pragma unroll
        for (int j = 0; j < 16; ++j) {
            float v = o[j] * inv + b1[chb + j];
            v = v > 0.f ? v : (__expf(v) - 1.0f);   // ELU (cheap form)
            r[j] = (__bf16)v;
        }
        *(uint4*)&OUT[(size_t)d * D1 + chb]     = *(uint4*)&r[0];
        *(uint4*)&OUT[(size_t)d * D1 + chb + 8] = *(uint4*)&r[8];
    }
}

// ---------------- GEMM2 (MFMA, no LDS) + layer-2 logits, bf16 H2 ------------
__global__ __launch_bounds__(256) void k_gemm2_mfma(const __bf16* __restrict__ A,
                                                    const __bf16* __restrict__ Wt2,
                                                    const float* __restrict__ as2v,
                                                    const float* __restrict__ ad2v,
                                                    __bf16* __restrict__ H2,
                                                    float* __restrict__ a_src2,
                                                    float* __restrict__ a_dst2) {
    int tid = threadIdx.x;
    int wid = tid >> 6, lane = tid & 63;
    int lq = lane >> 4, lm = lane & 15;
    int row0 = blockIdx.x * 64 + wid * 16;
    int arow = row0 + lm;
    const __bf16* ap = A + (size_t)(arow < N_NODES ? arow : 0) * D1;
    f32x4 acc = {};
    #pragma unroll
    for (int k0 = 0; k0 < 16; ++k0) {
        bf16x8 af  = *(const bf16x8*)&ap[k0 * 32 + lq * 8];
        bf16x8 bfr = *(const bf16x8*)&Wt2[lm * D1 + k0 * 32 + lq * 8];
        acc = __builtin_amdgcn_mfma_f32_16x16x32_bf16(af, bfr, acc, 0, 0, 0);
    }
    float as_c = as2v[lm], ad_c = ad2v[lm];
    #pragma unroll
    for (int r = 0; r < 4; ++r) {
        int gr = row0 + lq * 4 + r;
        float v = acc[r];
        if (gr < N_NODES) H2[gr * OUT_CH + lm] = (__bf16)v;
        float ps = v * as_c, pd = v * ad_c;
        #pragma unroll
        for (int off = 1; off < 16; off <<= 1) {
            ps += __shfl_xor(ps, off);
            pd += __shfl_xor(pd, off);
        }
        if (lm == 0 && gr < N_NODES) { a_src2[gr] = ps; a_dst2[gr] = pd; }
    }
}

// ---- agg2 edge-pair body ----------------------------------------------------
__device__ inline void agg2_pair(const __bf16* __restrict__ H2,
                                 const float* __restrict__ a_src,
                                 int s0, int s1, int c, float ad,
                                 float& o, float& lsum) {
    float h0 = (float)H2[s0 * OUT_CH + c];
    float h1 = (float)H2[s1 * OUT_CH + c];
    float wt0 = leaky_exp(a_src[s0] + ad);
    float wt1 = leaky_exp(a_src[s1] + ad);
    lsum += wt0 + wt1;
    o += wt0 * h0 + wt1 * h1;
}

// ---------------- layer-2 aggregation + csr pipeline + log_softmax ----------
__global__ __launch_bounds__(256) void k_agg2(const __bf16* __restrict__ H2,
                                              const float* __restrict__ a_src,
                                              const float* __restrict__ a_dst,
                                              const int* __restrict__ offsets,
                                              const int* __restrict__ deg,
                                              const int* __restrict__ csr,
                                              const float* __restrict__ b2,
                                              float* __restrict__ OUT) {
    int wave = (blockIdx.x * blockDim.x + threadIdx.x) >> 6;
    int lane = threadIdx.x & 63;
    if (wave >= N_NODES) return;
    int d = wave;
    int g = lane >> 4, c = lane & 15;
    float ad = a_dst[d];
    float o = 0.f, lsum = 0.f;
    if (g == 0) {
        float wself = leaky_exp(a_src[d] + ad);
        o = wself * (float)H2[d * OUT_CH + c];
        lsum = wself;
    }
    int beg = offsets[d], end = beg + deg[d];
    int i0 = beg + g;
    if (i0 + 4 < end) {
        int s0 = csr[i0], s1 = csr[i0 + 4];
        for (; i0 + 12 < end; i0 += 8) {
            int t0 = csr[i0 + 8], t1 = csr[i0 + 12];   // prefetch next pair
            agg2_pair(H2, a_src, s0, s1, c, ad, o, lsum);
            s0 = t0; s1 = t1;
        }
        agg2_pair(H2, a_src, s0, s1, c, ad, o, lsum);  // drain
        i0 += 8;
    }
    for (; i0 < end; i0 += 4) {          // tail
        int s = csr[i0];
        float wt = leaky_exp(a_src[s] + ad);
        float h = (float)H2[s * OUT_CH + c];
        lsum += wt;
        o += wt * h;
    }
    o += __shfl_xor(o, 16);  o += __shfl_xor(o, 32);
    lsum += __shfl_xor(lsum, 16);  lsum += __shfl_xor(lsum, 32);
    float v = o / (lsum + 1e-16f) + b2[c];
    float mx = v;
    #pragma unroll
    for (int off = 1; off < 16; off <<= 1) mx = fmaxf(mx, __shfl_xor(mx, off));
    float se = __expf(v - mx);
    #pragma unroll
    for (int off = 1; off < 16; off <<= 1) se += __shfl_xor(se, off);
    float res = v - mx - logf(se);
    if (lane < 16) OUT[d * OUT_CH + lane] = res;
}

// ---------------- launcher --------------------------------------------------
extern "C" void kernel_launch(void* const* d_in, const int* in_sizes, int n_in,
                              void* d_out, int out_size, void* d_ws, size_t ws_size,
                              hipStream_t stream) {
    const float* x        = (const float*)d_in[0];
    const int*   ei       = (const int*)d_in[1];
    const float* W1       = (const float*)d_in[2];
    const float* att_src1 = (const float*)d_in[3];
    const float* att_dst1 = (const float*)d_in[4];
    const float* b1       = (const float*)d_in[5];
    const float* W2       = (const float*)d_in[6];
    const float* att_src2 = (const float*)d_in[7];
    const float* att_dst2 = (const float*)d_in[8];
    const float* b2       = (const float*)d_in[9];
    float* out = (float*)d_out;

    const int* esrc = ei;
    const int* edst = ei + N_EDGES;

    char* ws = (char*)d_ws;
    size_t off = 0;
    auto alloc = [&](size_t bytes) { char* p = ws + off; off = (off + bytes + 255) & ~(size_t)255; return p; };
    unsigned char* Hf8 = (unsigned char*)alloc((size_t)N_NODES * D1); // 25.6 MB
    __bf16* out1   = (__bf16*)alloc((size_t)N_NODES * D1 * 2);        // 51.2 MB
    __bf16* Wt     = (__bf16*)alloc((size_t)D1 * IN_CH * 2);
    __bf16* Wt2    = (__bf16*)alloc((size_t)D1 * OUT_CH * 2);
    float* a_src1  = (float*)alloc((size_t)N_NODES * HEADS * 4);
    float* a_dst1  = (float*)alloc((size_t)N_NODES * HEADS * 4);
    __bf16* h2     = (__bf16*)alloc((size_t)N_NODES * OUT_CH * 2);    // 1.6 MB
    float* a_src2  = (float*)alloc((size_t)N_NODES * 4);
    float* a_dst2  = (float*)alloc((size_t)N_NODES * 4);
    int*   deg     = (int*)alloc((size_t)N_NODES * 4 + 256);          // +counter
    int*   counter = deg + N_NODES;
    int*   offsets = (int*)alloc((size_t)(N_NODES + 1) * 4);
    int*   cursor  = (int*)alloc((size_t)N_NODES * 4);
    int*   csr     = (int*)alloc((size_t)N_EDGES * 4);
    (void)ws_size;

    // 0. prep: W converts + zero deg/counter (memset dispatch eliminated)
    k_prep<<<512, 256, 0, stream>>>(W1, W2, Wt, Wt2, deg, counter);
    // 1. GEMM1 + att1 logits (fp8 H out), with histogram riding in CU holes
    k_gemm1e<<<G1B + HISTB, 512, 0, stream>>>(x, Wt, att_src1, att_dst1,
                                              Hf8, a_src1, a_dst1, edst, deg);
    // 2. CSR build: single-kernel range allocation + scatter
    int nb = (N_NODES + 1023) / 1024;
    k_csr<<<nb, 1024, 0, stream>>>(deg, counter, offsets, cursor);
    k_scatter<<<(N_EDGES + 255) / 256, 256, 0, stream>>>(esrc, edst, cursor, csr);
    // 3. layer-1 aggregation (+bias+ELU), pair-edge gather + index pipeline
    k_agg1<<<(N_NODES * 64 + 255) / 256, 256, 0, stream>>>(Hf8, a_src1, a_dst1,
                                                           offsets, deg, csr, b1, out1);
    // 4. GEMM2 (MFMA) + layer-2 logits, bf16 H2
    k_gemm2_mfma<<<(N_NODES + 63) / 64, 256, 0, stream>>>(out1, Wt2, att_src2, att_dst2, h2, a_src2, a_dst2);
    // 5. layer-2 aggregation (inline weights) + log_softmax
    k_agg2<<<(N_NODES * 64 + 255) / 256, 256, 0, stream>>>(h2, a_src2, a_dst2,
                                                           offsets, deg, csr, b2, out);
}